// Round 1
// baseline (926.300 us; speedup 1.0000x reference)
//
#include <hip/hip_runtime.h>
#include <hip/hip_bf16.h>

// CTC loss, fp32. T=1024, B=32, C=1024, L=128 fixed by the harness problem.
#define T_DIM 1024
#define B_DIM 32
#define C_DIM 1024
#define L_DIM 128
#define S_DIM 257          // 2*L+1 extended states
#define E_DIM 129          // blank + L label emissions per (t,b)
#define NEGF (-1e30f)

// ---------------- Kernel 1: log-softmax denom + emission gather ----------------
// One wave (64 lanes) per row (row = t*B + b). Each lane reads 4x float4
// (coalesced 1 KiB/instr across the wave), reduces max then sum(exp) via
// shfl_xor butterflies, then gathers the 129 needed classes (L1-hot: the row
// was just read by this wave).
__global__ __launch_bounds__(256) void emit_kernel(const float* __restrict__ data,
                                                   const int* __restrict__ labels,
                                                   float* __restrict__ emit) {
    const int wave = threadIdx.x >> 6;
    const int lane = threadIdx.x & 63;
    const int row = blockIdx.x * 4 + wave;           // row = t*B + b
    if (row >= T_DIM * B_DIM) return;
    const int b = row & (B_DIM - 1);

    const float4* d4 = (const float4*)(data + (size_t)row * C_DIM);
    float4 v[4];
    float m = -3.4e38f;
#pragma unroll
    for (int k = 0; k < 4; ++k) {
        v[k] = d4[lane + 64 * k];
        m = fmaxf(m, fmaxf(fmaxf(v[k].x, v[k].y), fmaxf(v[k].z, v[k].w)));
    }
#pragma unroll
    for (int off = 32; off >= 1; off >>= 1)
        m = fmaxf(m, __shfl_xor(m, off, 64));
    float s = 0.f;
#pragma unroll
    for (int k = 0; k < 4; ++k)
        s += __expf(v[k].x - m) + __expf(v[k].y - m) +
             __expf(v[k].z - m) + __expf(v[k].w - m);
#pragma unroll
    for (int off = 32; off >= 1; off >>= 1)
        s += __shfl_xor(s, off, 64);
    const float lse = m + __logf(s);

    const float* drow = data + (size_t)row * C_DIM;
    const int* lab = labels + b * L_DIM;
    float* erow = emit + (size_t)row * E_DIM;
    for (int j = lane; j < E_DIM; j += 64) {
        const int c = (j == 0) ? 0 : lab[j - 1];
        erow[j] = drow[c] - lse;
    }
}

// ---------------- Kernel 2: alpha DP ----------------
// One block per batch element b. 256 threads cover 257 states (tid 0 also
// handles s=256). LDS double-buffered alpha; one barrier per timestep.
// Emission for step t+1 is prefetched into registers while step t computes.
__global__ __launch_bounds__(256) void dp_kernel(const float* __restrict__ emit,
                                                 const int* __restrict__ labels,
                                                 const int* __restrict__ label_length,
                                                 const int* __restrict__ data_length,
                                                 float* __restrict__ out) {
    const int b = blockIdx.x;
    const int tid = threadIdx.x;
    __shared__ float alpha[2][S_DIM];

    const int* lab = labels + b * L_DIM;
    const int len = label_length[b];
    const int dlen = data_length[b];

    // Per-thread static state info for s = tid (+ s = tid+256 for tid==0).
    // j(s): emission index; skip(s): is the s-2 transition legal.
    int   jA[2];
    int   skipA[2];   // 0/1
    int   nstates = 0;
    for (int s = tid; s < S_DIM; s += 256) {
        jA[nstates] = (s & 1) ? ((s + 1) >> 1) : 0;
        int allow = 0;
        if ((s & 1) && s >= 3) {                      // odd state with a valid s-2 label
            const int l = (s - 1) >> 1;               // current label index (>=1 here)
            allow = (lab[l] != lab[l - 1]) ? 1 : 0;
        }
        skipA[nstates] = allow;
        ++nstates;
    }

    // t = 0 init: only s<2 live.
    {
        const float* erow0 = emit + (size_t)b * E_DIM;  // t=0 row
        int c = 0;
        for (int s = tid; s < S_DIM; s += 256, ++c)
            alpha[0][s] = (s < 2) ? erow0[jA[c]] : NEGF;
    }
    __syncthreads();

    // Prefetch emission for t=1.
    float ePre[2];
    {
        const float* erow = emit + (size_t)(1 * B_DIM + b) * E_DIM;
        for (int c = 0; c < nstates; ++c) ePre[c] = erow[jA[c]];
    }

    int cur = 0;
    for (int t = 1; t < dlen; ++t) {
        const int nxt = cur ^ 1;
        float eNow[2];
        for (int c = 0; c < nstates; ++c) eNow[c] = ePre[c];
        if (t + 1 < dlen) {   // issue next step's loads early (overlap barrier+compute)
            const float* erow = emit + (size_t)((t + 1) * B_DIM + b) * E_DIM;
            for (int c = 0; c < nstates; ++c) ePre[c] = erow[jA[c]];
        }
        int c = 0;
        for (int s = tid; s < S_DIM; s += 256, ++c) {
            const float a0 = alpha[cur][s];
            const float a1 = (s >= 1) ? alpha[cur][s - 1] : NEGF;
            const float a2 = skipA[c] ? alpha[cur][s - 2] : NEGF;
            const float mx = fmaxf(a0, fmaxf(a1, a2));
            const float r = mx + __logf(__expf(a0 - mx) + __expf(a1 - mx) + __expf(a2 - mx));
            alpha[nxt][s] = r + eNow[c];
        }
        __syncthreads();
        cur = nxt;
    }

    if (tid == 0) {
        const float ab = alpha[cur][2 * len];
        const float al = alpha[cur][2 * len - 1];
        const float mx = fmaxf(ab, al);
        const float loss = -(mx + __logf(__expf(ab - mx) + __expf(al - mx)));
        atomicAdd(out, loss * (1.0f / B_DIM));
    }
}

extern "C" void kernel_launch(void* const* d_in, const int* in_sizes, int n_in,
                              void* d_out, int out_size, void* d_ws, size_t ws_size,
                              hipStream_t stream) {
    const int*   labels       = (const int*)d_in[0];
    const float* data         = (const float*)d_in[1];
    const int*   label_length = (const int*)d_in[2];
    const int*   data_length  = (const int*)d_in[3];
    float*       out          = (float*)d_out;
    float*       emit         = (float*)d_ws;   // T*B*E floats = 16.9 MB

    hipMemsetAsync(d_out, 0, sizeof(float), stream);

    const int rows = T_DIM * B_DIM;
    emit_kernel<<<rows / 4, 256, 0, stream>>>(data, labels, emit);
    dp_kernel<<<B_DIM, 256, 0, stream>>>(emit, labels, label_length, data_length, out);
}

// Round 2
// 287.679 us; speedup vs baseline: 3.2199x; 3.2199x over previous
//
#include <hip/hip_runtime.h>
#include <hip/hip_bf16.h>

// CTC loss, fp32 in / fp32 out. T=1024, B=32, C=1024, L=128 fixed.
// R2: linear-domain fp64 register DP, one wave per batch element,
//     no barriers / no LDS / no transcendentals in the inner loop.
#define T_DIM 1024
#define B_DIM 32
#define C_DIM 1024
#define L_DIM 128
#define S_DIM 257

// ---------------- Kernel 1: log-softmax + linear emission gather ----------------
// One wave per row (row = t*B + b). Writes LINEAR probabilities:
//   epair[row*64 + l] = (p(label 2l), p(label 2l+1))   (0-based label idx)
//   eblank[b*T + t]   = p(class 0)
__global__ __launch_bounds__(256) void emit_kernel(const float* __restrict__ data,
                                                   const int* __restrict__ labels,
                                                   float2* __restrict__ epair,
                                                   float* __restrict__ eblank) {
    const int wave = threadIdx.x >> 6;
    const int lane = threadIdx.x & 63;
    const int row = blockIdx.x * 4 + wave;           // row = t*B + b
    const int b = row & (B_DIM - 1);
    const int t = row >> 5;                          // B = 32

    const float4* d4 = (const float4*)(data + (size_t)row * C_DIM);
    float4 v[4];
    float m = -3.4e38f;
#pragma unroll
    for (int k = 0; k < 4; ++k) {
        v[k] = d4[lane + 64 * k];
        m = fmaxf(m, fmaxf(fmaxf(v[k].x, v[k].y), fmaxf(v[k].z, v[k].w)));
    }
#pragma unroll
    for (int off = 32; off >= 1; off >>= 1)
        m = fmaxf(m, __shfl_xor(m, off, 64));
    float s = 0.f;
#pragma unroll
    for (int k = 0; k < 4; ++k)
        s += __expf(v[k].x - m) + __expf(v[k].y - m) +
             __expf(v[k].z - m) + __expf(v[k].w - m);
#pragma unroll
    for (int off = 32; off >= 1; off >>= 1)
        s += __shfl_xor(s, off, 64);
    const float lse = m + __logf(s);

    const float* drow = data + (size_t)row * C_DIM;
    const int2 cc = ((const int2*)(labels + b * L_DIM))[lane];   // labels 2l, 2l+1
    float2 pr;
    pr.x = __expf(drow[cc.x] - lse);
    pr.y = __expf(drow[cc.y] - lse);
    epair[(size_t)row * 64 + lane] = pr;
    if (lane == 0) eblank[b * T_DIM + t] = __expf(drow[0] - lse);
}

// ---------------- Kernel 2: alpha DP (wave-synchronous, linear fp64) ----------------
// One 64-thread block per b. Lane l owns states 4l..4l+3 (lane 63 also 256).
// Per step: 1 shfl_up + ~12 f64 ops. Renorm (power-of-2) every 32 steps.
__global__ __launch_bounds__(64) void dp_kernel(const float2* __restrict__ epair,
                                                const float* __restrict__ eblank,
                                                const int* __restrict__ labels,
                                                const int* __restrict__ label_length,
                                                const int* __restrict__ data_length,
                                                float* __restrict__ out) {
    const int b = blockIdx.x;
    const int l = threadIdx.x;
    const int* lab = labels + b * L_DIM;
    const int len = label_length[b];
    const int dlen = data_length[b];

    const int2 cc = ((const int2*)lab)[l];            // labels 2l, 2l+1 (0-based)
    const int cprev = (l > 0) ? lab[2 * l - 1] : -1;
    const bool skip1 = (l > 0) && (cc.x != cprev);    // state 4l+1 s-2 transition
    const bool skip3 = (cc.y != cc.x);                // state 4l+3 s-2 transition

    const float* ebrow = eblank + b * T_DIM;

    // t = 0 init (linear domain): only states 0,1 live.
    double a0, a1, a2 = 0.0, a3 = 0.0, a4 = 0.0;
    {
        const float2 e0 = epair[(size_t)b * 64 + l];
        const float eb0 = ebrow[0];
        a0 = (l == 0) ? (double)eb0 : 0.0;
        a1 = (l == 0) ? (double)e0.x : 0.0;
    }
    long long kacc = 0;   // accumulated power-of-2 scale: true = stored * 2^kacc

    auto step = [&](float2 epv, float ebv) {
        const double e1 = (double)epv.x, e2 = (double)epv.y, eb = (double)ebv;
        double h = __shfl_up(a3, 1, 64);              // alpha[4l-1] from lane l-1
        if (l == 0) h = 0.0;
        const double n0 = (a0 + h) * eb;
        const double n1 = (a1 + a0 + (skip1 ? h : 0.0)) * e1;
        const double n2 = (a2 + a1) * eb;
        const double n3 = (a3 + a2 + (skip3 ? a1 : 0.0)) * e2;
        const double n4 = (a4 + a3) * eb;
        a0 = n0; a1 = n1; a2 = n2; a3 = n3; a4 = n4;
    };

    auto renorm = [&]() {
        double m = fmax(fmax(fmax(a0, a1), fmax(a2, a3)), a4);
#pragma unroll
        for (int off = 32; off >= 1; off >>= 1)
            m = fmax(m, __shfl_xor(m, off, 64));
        const long long mb = __double_as_longlong(m);
        const int ex = (int)((mb >> 52) & 0x7ff) - 1023;   // m in [2^ex, 2^{ex+1})
        const double sc = __longlong_as_double((long long)(1023 - ex) << 52);
        a0 *= sc; a1 *= sc; a2 *= sc; a3 *= sc; a4 *= sc;
        kacc += ex;
    };

    float2 bufA[8], bufB[8];
    float ebA[8], ebB[8];

    auto load_chunk = [&](int c, float2* ep8, float* eb8) {
#pragma unroll
        for (int j = 0; j < 8; ++j) {
            int t = 1 + 8 * c + j;
            int tc = (t < T_DIM) ? t : (T_DIM - 1);
            ep8[j] = epair[(size_t)(tc * B_DIM + b) * 64 + l];
            eb8[j] = ebrow[tc];
        }
    };

    auto compute_chunk = [&](int c, const float2* ep8, const float* eb8) {
        const int t0 = 1 + 8 * c;
        if (t0 + 7 < dlen) {
#pragma unroll
            for (int j = 0; j < 8; ++j) step(ep8[j], eb8[j]);
        } else {
#pragma unroll
            for (int j = 0; j < 8; ++j)
                if (t0 + j < dlen) step(ep8[j], eb8[j]);
        }
    };

    const int nch = (dlen - 1 + 7) / 8;   // 8-step chunks covering t = 1..dlen-1
    load_chunk(0, bufA, ebA);
    for (int c = 0; c < nch; c += 2) {
        load_chunk(c + 1, bufB, ebB);     // prefetch next chunk while computing this one
        compute_chunk(c, bufA, ebA);
        load_chunk(c + 2, bufA, ebA);
        compute_chunk(c + 1, bufB, ebB);
        if (((c + 1) & 3) == 3) renorm(); // every 4 chunks = 32 steps
    }

    // Extract alpha[2*len] + alpha[2*len-1] via LDS (one-time).
    __shared__ double fin[S_DIM];
    fin[4 * l + 0] = a0; fin[4 * l + 1] = a1;
    fin[4 * l + 2] = a2; fin[4 * l + 3] = a3;
    if (l == 63) fin[256] = a4;
    __syncthreads();
    if (l == 0) {
        const double v = fin[2 * len] + fin[2 * len - 1];
        const long long vb = __double_as_longlong(v);
        const int ve = (int)((vb >> 52) & 0x7ff) - 1023;
        const double mant = __longlong_as_double(
            (vb & 0x000FFFFFFFFFFFFFLL) | (1023LL << 52));        // [1,2)
        const double l2 = (double)__log2f((float)mant) + (double)ve + (double)kacc;
        const float loss = (float)(-l2 * 0.6931471805599453);
        atomicAdd(out, loss * (1.0f / B_DIM));
    }
}

extern "C" void kernel_launch(void* const* d_in, const int* in_sizes, int n_in,
                              void* d_out, int out_size, void* d_ws, size_t ws_size,
                              hipStream_t stream) {
    const int*   labels       = (const int*)d_in[0];
    const float* data         = (const float*)d_in[1];
    const int*   label_length = (const int*)d_in[2];
    const int*   data_length  = (const int*)d_in[3];
    float*       out          = (float*)d_out;

    // Workspace layout: epair [T*B*64 float2] = 16 MiB, then eblank [B*T floats].
    float2* epair  = (float2*)d_ws;
    float*  eblank = (float*)((char*)d_ws + (size_t)T_DIM * B_DIM * 64 * sizeof(float2));

    hipMemsetAsync(d_out, 0, sizeof(float), stream);

    const int rows = T_DIM * B_DIM;
    emit_kernel<<<rows / 4, 256, 0, stream>>>(data, labels, epair, eblank);
    dp_kernel<<<B_DIM, 64, 0, stream>>>(epair, eblank, labels, label_length,
                                        data_length, out);
}

// Round 3
// 271.252 us; speedup vs baseline: 3.4149x; 1.0606x over previous
//
#include <hip/hip_runtime.h>
#include <hip/hip_bf16.h>

// CTC loss, fp32 in / fp32 out. T=1024, B=32, C=1024, L=128 fixed.
// R3: fix R2's collapsed software pipeline (VGPR=36 showed loads were sunk
// to uses). 16-step register double-buffer + sched_barrier(0) pinning +
// __launch_bounds__(64,1) so the allocator keeps buffers live.
#define T_DIM 1024
#define B_DIM 32
#define C_DIM 1024
#define L_DIM 128
#define S_DIM 257
#define TPAD  (T_DIM + 64)   // padded t-rows so prefetch needs no clamping

// ---------------- Kernel 1: log-softmax + linear emission gather ----------------
// One wave per row (row = t*B + b). Writes LINEAR probabilities:
//   epair[(t*B+b)*64 + l] = (p(label 2l), p(label 2l+1))
//   eblank[b*TPAD + t]    = p(class 0)
__global__ __launch_bounds__(256) void emit_kernel(const float* __restrict__ data,
                                                   const int* __restrict__ labels,
                                                   float2* __restrict__ epair,
                                                   float* __restrict__ eblank) {
    const int wave = threadIdx.x >> 6;
    const int lane = threadIdx.x & 63;
    const int row = blockIdx.x * 4 + wave;           // row = t*B + b
    const int b = row & (B_DIM - 1);
    const int t = row >> 5;                          // B = 32

    const float4* d4 = (const float4*)(data + (size_t)row * C_DIM);
    float4 v[4];
    float m = -3.4e38f;
#pragma unroll
    for (int k = 0; k < 4; ++k) {
        v[k] = d4[lane + 64 * k];
        m = fmaxf(m, fmaxf(fmaxf(v[k].x, v[k].y), fmaxf(v[k].z, v[k].w)));
    }
#pragma unroll
    for (int off = 32; off >= 1; off >>= 1)
        m = fmaxf(m, __shfl_xor(m, off, 64));
    float s = 0.f;
#pragma unroll
    for (int k = 0; k < 4; ++k)
        s += __expf(v[k].x - m) + __expf(v[k].y - m) +
             __expf(v[k].z - m) + __expf(v[k].w - m);
#pragma unroll
    for (int off = 32; off >= 1; off >>= 1)
        s += __shfl_xor(s, off, 64);
    const float lse = m + __logf(s);

    const float* drow = data + (size_t)row * C_DIM;
    const int2 cc = ((const int2*)(labels + b * L_DIM))[lane];   // labels 2l, 2l+1
    float2 pr;
    pr.x = __expf(drow[cc.x] - lse);
    pr.y = __expf(drow[cc.y] - lse);
    epair[(size_t)row * 64 + lane] = pr;
    if (lane == 0) eblank[b * TPAD + t] = __expf(drow[0] - lse);
}

// ---------------- Kernel 2: alpha DP (wave-synchronous, linear fp64) ----------------
// One 64-thread block per b. Lane l owns states 4l..4l+3 (lane 63 also 256).
// Per step: 1 shfl_up + 12 f64 VALU ops. Power-of-2 renorm every 32 steps.
// Emissions register-double-buffered in 16-step chunks; sched_barrier(0)
// keeps the loads from sinking into the consuming chunk.
__global__ __launch_bounds__(64, 1) void dp_kernel(const float2* __restrict__ epair,
                                                   const float* __restrict__ eblank,
                                                   const int* __restrict__ labels,
                                                   const int* __restrict__ label_length,
                                                   const int* __restrict__ data_length,
                                                   float* __restrict__ lossbuf) {
    const int b = blockIdx.x;
    const int l = threadIdx.x;
    const int* lab = labels + b * L_DIM;
    const int len = label_length[b];
    const int dlen = data_length[b];

    const int2 cc = ((const int2*)lab)[l];            // labels 2l, 2l+1 (0-based)
    const int cprev = (l > 0) ? lab[2 * l - 1] : -1;
    const double skip1d = ((l > 0) && (cc.x != cprev)) ? 1.0 : 0.0;  // state 4l+1
    const double skip3d = (cc.y != cc.x) ? 1.0 : 0.0;                // state 4l+3

    const float* ebrow = eblank + b * TPAD;

    // t = 0 init (linear domain): only states 0,1 live.
    double a0, a1, a2 = 0.0, a3 = 0.0, a4 = 0.0;
    {
        const float2 e0 = epair[(size_t)b * 64 + l];
        const float eb0 = ebrow[0];
        a0 = (l == 0) ? (double)eb0 : 0.0;
        a1 = (l == 0) ? (double)e0.x : 0.0;
    }
    long long kacc = 0;   // accumulated power-of-2 scale: true = stored * 2^kacc

    auto step = [&](float2 epv, float ebv) {
        const double e1 = (double)epv.x, e2 = (double)epv.y, eb = (double)ebv;
        double h = __shfl_up(a3, 1, 64);              // alpha[4l-1] from lane l-1
        if (l == 0) h = 0.0;
        const double n0 = (a0 + h) * eb;
        const double n1 = fma(skip1d, h, a1 + a0) * e1;
        const double n2 = (a2 + a1) * eb;
        const double n3 = fma(skip3d, a1, a3 + a2) * e2;
        const double n4 = (a4 + a3) * eb;
        a0 = n0; a1 = n1; a2 = n2; a3 = n3; a4 = n4;
    };

    auto renorm = [&]() {
        double m = fmax(fmax(fmax(a0, a1), fmax(a2, a3)), a4);
#pragma unroll
        for (int off = 32; off >= 1; off >>= 1)
            m = fmax(m, __shfl_xor(m, off, 64));
        const long long mb = __double_as_longlong(m);
        const int ex = (int)((mb >> 52) & 0x7ff) - 1023;   // m in [2^ex, 2^{ex+1})
        const double sc = __longlong_as_double((long long)(1023 - ex) << 52);
        a0 *= sc; a1 *= sc; a2 *= sc; a3 *= sc; a4 *= sc;
        kacc += ex;
    };

    float2 bufA[16], bufB[16];
    float ebA[16], ebB[16];

    auto load_chunk = [&](int c, float2* ep, float* eb) {
        const int t0 = 1 + 16 * c;                    // t0+15 <= 1+16*65+15 < TPAD
#pragma unroll
        for (int j = 0; j < 16; ++j) {
            ep[j] = epair[(size_t)((t0 + j) * B_DIM + b) * 64 + l];
            eb[j] = ebrow[t0 + j];
        }
    };

    auto compute_chunk = [&](int c, const float2* ep, const float* eb) {
        const int t0 = 1 + 16 * c;
        if (t0 + 15 < dlen) {
#pragma unroll
            for (int j = 0; j < 16; ++j) step(ep[j], eb[j]);
        } else {
#pragma unroll
            for (int j = 0; j < 16; ++j)
                if (t0 + j < dlen) step(ep[j], eb[j]);   // dlen is wave-uniform
        }
    };

    const int nch = (dlen - 1 + 15) / 16;   // 16-step chunks covering t = 1..dlen-1
    load_chunk(0, bufA, ebA);
    load_chunk(1, bufB, ebB);
    __builtin_amdgcn_sched_barrier(0);
    for (int c = 0; c < nch; c += 2) {
        compute_chunk(c, bufA, ebA);
        load_chunk(c + 2, bufA, ebA);
        __builtin_amdgcn_sched_barrier(0);
        compute_chunk(c + 1, bufB, ebB);
        load_chunk(c + 3, bufB, ebB);
        __builtin_amdgcn_sched_barrier(0);
        renorm();                          // every 32 steps; f64 range is ample
    }

    // Extract alpha[2*len] + alpha[2*len-1] via LDS (one-time).
    __shared__ double fin[S_DIM];
    fin[4 * l + 0] = a0; fin[4 * l + 1] = a1;
    fin[4 * l + 2] = a2; fin[4 * l + 3] = a3;
    if (l == 63) fin[256] = a4;
    __syncthreads();
    if (l == 0) {
        const double v = fin[2 * len] + fin[2 * len - 1];
        const long long vb = __double_as_longlong(v);
        const int ve = (int)((vb >> 52) & 0x7ff) - 1023;
        const double mant = __longlong_as_double(
            (vb & 0x000FFFFFFFFFFFFFLL) | (1023LL << 52));        // [1,2)
        const double l2 = (double)__log2f((float)mant) + (double)ve + (double)kacc;
        lossbuf[b] = (float)(-l2 * 0.6931471805599453);
    }
}

// ---------------- Kernel 3: mean over batch ----------------
__global__ __launch_bounds__(64) void final_kernel(const float* __restrict__ lossbuf,
                                                   float* __restrict__ out) {
    const int l = threadIdx.x;
    float v = (l < B_DIM) ? lossbuf[l] : 0.f;
#pragma unroll
    for (int off = 32; off >= 1; off >>= 1)
        v += __shfl_xor(v, off, 64);
    if (l == 0) out[0] = v * (1.0f / B_DIM);
}

extern "C" void kernel_launch(void* const* d_in, const int* in_sizes, int n_in,
                              void* d_out, int out_size, void* d_ws, size_t ws_size,
                              hipStream_t stream) {
    const int*   labels       = (const int*)d_in[0];
    const float* data         = (const float*)d_in[1];
    const int*   label_length = (const int*)d_in[2];
    const int*   data_length  = (const int*)d_in[3];
    float*       out          = (float*)d_out;

    // Workspace: epair [TPAD*B*64 float2] (padded), then eblank [B*TPAD], then lossbuf [B].
    float2* epair  = (float2*)d_ws;
    float*  eblank = (float*)((char*)d_ws + (size_t)TPAD * B_DIM * 64 * sizeof(float2));
    float*  lossb  = eblank + (size_t)B_DIM * TPAD;

    const int rows = T_DIM * B_DIM;
    emit_kernel<<<rows / 4, 256, 0, stream>>>(data, labels, epair, eblank);
    dp_kernel<<<B_DIM, 64, 0, stream>>>(epair, eblank, labels, label_length,
                                        data_length, lossb);
    final_kernel<<<1, 64, 0, stream>>>(lossb, out);
}

// Round 4
// 254.105 us; speedup vs baseline: 3.6453x; 1.0675x over previous
//
#include <hip/hip_runtime.h>
#include <hip/hip_bf16.h>

// CTC loss, fp32 in / fp32 out. T=1024, B=32, C=1024, L=128 fixed.
// R4: (a) meet-in-the-middle: forward alpha + backward beta halve the serial
//     chain (1023 -> ~511 steps); (b) emissions staged through LDS via
//     global_load_lds double-buffering (register prefetch was collapsed by
//     the allocator in R2/R3 - LDS staging can't be).
#define T_DIM 1024
#define B_DIM 32
#define C_DIM 1024
#define L_DIM 128
#define S_DIM 257
#define CH    32          // timesteps per staged chunk

// ---- workspace layout (bytes) ----
#define WS_EPAIR   0                         // [B][T][64] float2 = 16 MiB (b-major!)
#define WS_EBLANK  (32u * 1024u * 64u * 8u)  // [B][T] float
#define WS_ALPHA   (WS_EBLANK + 32u * 1024u * 4u)   // [B][264] double
#define WS_BETA    (WS_ALPHA + 32u * 264u * 8u)     // [B][264] double (257,258 = 0)
#define WS_KACC    (WS_BETA + 32u * 264u * 8u)      // [B][2] long long
#define WS_LOSS    (WS_KACC + 32u * 2u * 8u)        // [B] float

// ---------------- Kernel 1: log-softmax + linear emission gather ----------------
__global__ __launch_bounds__(256) void emit_kernel(const float* __restrict__ data,
                                                   const int* __restrict__ labels,
                                                   float2* __restrict__ epair,
                                                   float* __restrict__ eblank) {
    const int wave = threadIdx.x >> 6;
    const int lane = threadIdx.x & 63;
    const int row = blockIdx.x * 4 + wave;           // row = t*B + b
    const int b = row & (B_DIM - 1);
    const int t = row >> 5;                          // B = 32

    const float4* d4 = (const float4*)(data + (size_t)row * C_DIM);
    float4 v[4];
    float m = -3.4e38f;
#pragma unroll
    for (int k = 0; k < 4; ++k) {
        v[k] = d4[lane + 64 * k];
        m = fmaxf(m, fmaxf(fmaxf(v[k].x, v[k].y), fmaxf(v[k].z, v[k].w)));
    }
#pragma unroll
    for (int off = 32; off >= 1; off >>= 1)
        m = fmaxf(m, __shfl_xor(m, off, 64));
    float s = 0.f;
#pragma unroll
    for (int k = 0; k < 4; ++k)
        s += __expf(v[k].x - m) + __expf(v[k].y - m) +
             __expf(v[k].z - m) + __expf(v[k].w - m);
#pragma unroll
    for (int off = 32; off >= 1; off >>= 1)
        s += __shfl_xor(s, off, 64);
    const float lse = m + __logf(s);

    const float* drow = data + (size_t)row * C_DIM;
    const int2 cc = ((const int2*)(labels + b * L_DIM))[lane];   // labels 2l, 2l+1
    float2 pr;
    pr.x = __expf(drow[cc.x] - lse);
    pr.y = __expf(drow[cc.y] - lse);
    epair[((size_t)b * T_DIM + t) * 64 + lane] = pr;             // b-major rows
    if (lane == 0) eblank[b * T_DIM + t] = __expf(drow[0] - lse);
}

// ---------------- Kernel 2: alpha/beta DP ----------------
// grid = 64 blocks: b = blockIdx&31, dir = blockIdx>>5 (0=fwd alpha, 1=bwd beta).
// One wave per block. Lane l owns 4 states; one shfl_up(a3) per step in both
// directions (backward uses reversed state index r = 256-s).
__global__ __launch_bounds__(64, 1) void dp_kernel(const float2* __restrict__ epair,
                                                   const float* __restrict__ eblank,
                                                   const int* __restrict__ labels,
                                                   const int* __restrict__ label_length,
                                                   const int* __restrict__ data_length,
                                                   double* __restrict__ alphavec,
                                                   double* __restrict__ betavec,
                                                   long long* __restrict__ kaccs) {
    const int b   = blockIdx.x & (B_DIM - 1);
    const int dir = blockIdx.x >> 5;
    const int l = threadIdx.x;
    const int* lab = labels + b * L_DIM;
    const int len = label_length[b];
    const int dlen = data_length[b];
    const int m = dlen >> 1;          // split point: alpha(m-1) meets beta(m)

    __shared__ float2 ebuf[2][CH][64];   // 32 KiB double buffer
    __shared__ float  ebl[T_DIM];        // whole blank row, 4 KiB

    const float2* eprow = epair + (size_t)b * T_DIM * 64;
    const float*  ebrow = eblank + (size_t)b * T_DIM;

    // Stage entire blank row: 16 x (64 lanes x 4 B).
#pragma unroll
    for (int i = 0; i < T_DIM / 64; ++i)
        __builtin_amdgcn_global_load_lds(
            (const __attribute__((address_space(1))) void*)(ebrow + i * 64 + l),
            (__attribute__((address_space(3))) void*)(&ebl[i * 64]), 4, 0, 0);

    // Stage CH epair rows [trow0, trow0+CH) : 16 x (64 lanes x 16 B), 2 rows/instr.
    auto stage_chunk = [&](int cb, int trow0) {
#pragma unroll
        for (int i = 0; i < CH / 2; ++i)
            __builtin_amdgcn_global_load_lds(
                (const __attribute__((address_space(1))) void*)
                    ((const char*)(eprow + (size_t)(trow0 + 2 * i) * 64) + l * 16),
                (__attribute__((address_space(3))) void*)(&ebuf[cb][2 * i][0]), 16, 0, 0);
    };

    double a0 = 0.0, a1 = 0.0, a2 = 0.0, a3 = 0.0, a4 = 0.0;
    long long kacc = 0;

    auto renorm = [&]() {
        double mx = fmax(fmax(fmax(a0, a1), fmax(a2, a3)), a4);
        int hi = __double2hiint(mx);            // alphas >= 0: hi-word order = value order
#pragma unroll
        for (int off = 32; off >= 1; off >>= 1)
            hi = max(hi, __shfl_xor(hi, off, 64));
        const int ex = ((hi >> 20) & 0x7ff) - 1023;
        const double sc = __hiloint2double((1023 - ex) << 20, 0);   // 2^-ex
        a0 *= sc; a1 *= sc; a2 *= sc; a3 *= sc; a4 *= sc;
        kacc += ex;
    };

    if (dir == 0) {
        // ---------------- forward alpha: t = 0 .. m-1 ----------------
        const int2 cc = ((const int2*)lab)[l];                        // labels 2l, 2l+1
        const double skip1d = ((l > 0) && (cc.x != lab[2 * l - 1])) ? 1.0 : 0.0;
        const double skip3d = (cc.y != cc.x) ? 1.0 : 0.0;

        stage_chunk(0, 1);
        __builtin_amdgcn_s_waitcnt(0x0f70);     // vmcnt(0)

        {   // t = 0 init
            const float2 ep0 = eprow[l];
            a0 = (l == 0) ? (double)ebl[0] : 0.0;
            a1 = (l == 0) ? (double)ep0.x : 0.0;
        }

        const int nsteps = m - 1;               // t = 1 .. m-1
        const int nch = (nsteps + CH - 1) / CH;
        for (int c = 0; c < nch; ++c) {
            const int cb = c & 1;
            const bool more = (c + 1 < nch);
            if (more) stage_chunk(cb ^ 1, 1 + CH * (c + 1));
            __builtin_amdgcn_sched_barrier(0);
            const int t0 = 1 + CH * c;
            const bool full = (t0 + CH <= m);
#pragma unroll
            for (int j = 0; j < CH; ++j) {
                if (full || (t0 + j < m)) {
                    const float2 ep = ebuf[cb][j][l];
                    const double eb = (double)ebl[t0 + j];
                    double h = __shfl_up(a3, 1, 64);
                    if (l == 0) h = 0.0;
                    const double n0 = (a0 + h) * eb;
                    const double n1 = fma(skip1d, h, a1 + a0) * (double)ep.x;
                    const double n2 = (a2 + a1) * eb;
                    const double n3 = fma(skip3d, a1, a3 + a2) * (double)ep.y;
                    const double n4 = (a4 + a3) * eb;
                    a0 = n0; a1 = n1; a2 = n2; a3 = n3; a4 = n4;
                }
            }
            renorm();
            if (more) __builtin_amdgcn_s_waitcnt(0x0f70);
            __builtin_amdgcn_sched_barrier(0);
        }

        double* av = (double*)alphavec + b * 264;
        av[4 * l + 0] = a0; av[4 * l + 1] = a1;
        av[4 * l + 2] = a2; av[4 * l + 3] = a3;
        if (l == 63) av[256] = a4;
        if (l == 0) kaccs[2 * b + 0] = kacc;
    } else {
        // ---------------- backward beta: t = dlen-1 .. m (reversed states r=256-s) ----
        const int2 c2 = ((const int2*)lab)[63 - l];    // (lab[126-2l], lab[127-2l])
        const int labL = (l > 0) ? lab[128 - 2 * l] : -1;
        const double skip1d = ((l > 0) && (labL != c2.y)) ? 1.0 : 0.0;   // r=4l+1
        const double skip3d = (c2.y != c2.x) ? 1.0 : 0.0;                // r=4l+3

        stage_chunk(0, dlen - 1 - CH);          // rows [dlen-1-CH, dlen-2]
        __builtin_amdgcn_s_waitcnt(0x0f70);

        {   // init at t = dlen-1: beta = e * [s==2len || s==2len-1],  s = 256-r
            const float2 epi = eprow[(size_t)(dlen - 1) * 64 + (63 - l)];
            const double ebi = (double)ebl[dlen - 1];
            const int s0 = 256 - 4 * l;
            a0 = (s0 == 2 * len     || s0 == 2 * len - 1) ? ebi : 0.0;
            a1 = (s0 - 1 == 2 * len || s0 - 1 == 2 * len - 1) ? (double)epi.y : 0.0;
            a2 = (s0 - 2 == 2 * len || s0 - 2 == 2 * len - 1) ? ebi : 0.0;
            a3 = (s0 - 3 == 2 * len || s0 - 3 == 2 * len - 1) ? (double)epi.x : 0.0;
            a4 = 0.0;                            // lane63's r=256 is s=0, never terminal
        }

        const int nsteps = dlen - 1 - m;        // t = dlen-2 .. m
        const int nch = (nsteps + CH - 1) / CH;
        for (int c = 0; c < nch; ++c) {
            const int cb = c & 1;
            const bool more = (c + 1 < nch);
            const int thi = dlen - 2 - CH * c;
            const int tlo = thi - CH + 1;
            if (more) stage_chunk(cb ^ 1, tlo - CH);
            __builtin_amdgcn_sched_barrier(0);
            const bool full = (tlo >= m);
#pragma unroll
            for (int jj = 0; jj < CH; ++jj) {
                const int j = CH - 1 - jj;      // t descending
                const int t = tlo + j;
                if (full || (t >= m)) {
                    const float2 ep = ebuf[cb][j][63 - l];
                    const double eb = (double)ebl[t];
                    double h = __shfl_up(a3, 1, 64);
                    if (l == 0) h = 0.0;
                    const double n0 = (a0 + h) * eb;
                    const double n1 = fma(skip1d, h, a1 + a0) * (double)ep.y;
                    const double n2 = (a2 + a1) * eb;
                    const double n3 = fma(skip3d, a1, a3 + a2) * (double)ep.x;
                    const double n4 = (a4 + a3) * eb;
                    a0 = n0; a1 = n1; a2 = n2; a3 = n3; a4 = n4;
                }
            }
            renorm();
            if (more) __builtin_amdgcn_s_waitcnt(0x0f70);
            __builtin_amdgcn_sched_barrier(0);
        }

        double* bv = (double*)betavec + b * 264;     // natural s order
        bv[256 - 4 * l] = a0; bv[255 - 4 * l] = a1;
        bv[254 - 4 * l] = a2; bv[253 - 4 * l] = a3;
        if (l == 63) bv[0] = a4;
        if (l == 0) { bv[257] = 0.0; bv[258] = 0.0; kaccs[2 * b + 1] = kacc; }
    }
}

// ---------------- Kernel 3: combine alpha(m-1) x T x beta(m) ----------------
__global__ __launch_bounds__(64) void combine_kernel(const double* __restrict__ alphavec,
                                                     const double* __restrict__ betavec,
                                                     const long long* __restrict__ kaccs,
                                                     const int* __restrict__ labels,
                                                     float* __restrict__ lossbuf) {
    const int b = blockIdx.x;
    const int l = threadIdx.x;
    const double* A = alphavec + b * 264;
    const double* Bv = betavec + b * 264;
    const int* lab = labels + b * L_DIM;

    const double a0 = A[4 * l], a1 = A[4 * l + 1], a2 = A[4 * l + 2], a3 = A[4 * l + 3];
    const double b0 = Bv[4 * l], b1 = Bv[4 * l + 1], b2 = Bv[4 * l + 2];
    const double b3 = Bv[4 * l + 3], b4 = Bv[4 * l + 4], b5 = Bv[4 * l + 5];
    const double sk1 = (lab[2 * l + 1] != lab[2 * l]) ? 1.0 : 0.0;       // skip into 4l+3
    const int labn = (l < 63) ? lab[2 * l + 2] : -1;
    const double sk3 = ((l < 63) && (labn != lab[2 * l + 1])) ? 1.0 : 0.0; // skip into 4l+5

    double s = a0 * (b0 + b1)
             + a1 * (b1 + b2 + sk1 * b3)
             + a2 * (b2 + b3)
             + a3 * (b3 + b4 + sk3 * b5);
    if (l == 63) s += A[256] * Bv[256];

#pragma unroll
    for (int off = 32; off >= 1; off >>= 1)
        s += __shfl_xor(s, off, 64);

    if (l == 0) {
        const long long k = kaccs[2 * b] + kaccs[2 * b + 1];
        const long long vb = __double_as_longlong(s);
        const int ve = (int)((vb >> 52) & 0x7ff) - 1023;
        const double mant = __longlong_as_double(
            (vb & 0x000FFFFFFFFFFFFFLL) | (1023LL << 52));        // [1,2)
        const double l2 = (double)__log2f((float)mant) + (double)ve + (double)k;
        lossbuf[b] = (float)(-l2 * 0.6931471805599453);
    }
}

// ---------------- Kernel 4: mean over batch ----------------
__global__ __launch_bounds__(64) void final_kernel(const float* __restrict__ lossbuf,
                                                   float* __restrict__ out) {
    const int l = threadIdx.x;
    float v = (l < B_DIM) ? lossbuf[l] : 0.f;
#pragma unroll
    for (int off = 32; off >= 1; off >>= 1)
        v += __shfl_xor(v, off, 64);
    if (l == 0) out[0] = v * (1.0f / B_DIM);
}

extern "C" void kernel_launch(void* const* d_in, const int* in_sizes, int n_in,
                              void* d_out, int out_size, void* d_ws, size_t ws_size,
                              hipStream_t stream) {
    const int*   labels       = (const int*)d_in[0];
    const float* data         = (const float*)d_in[1];
    const int*   label_length = (const int*)d_in[2];
    const int*   data_length  = (const int*)d_in[3];
    float*       out          = (float*)d_out;

    char* ws = (char*)d_ws;
    float2*    epair    = (float2*)(ws + WS_EPAIR);
    float*     eblank   = (float*)(ws + WS_EBLANK);
    double*    alphavec = (double*)(ws + WS_ALPHA);
    double*    betavec  = (double*)(ws + WS_BETA);
    long long* kaccs    = (long long*)(ws + WS_KACC);
    float*     lossb    = (float*)(ws + WS_LOSS);

    const int rows = T_DIM * B_DIM;
    emit_kernel<<<rows / 4, 256, 0, stream>>>(data, labels, epair, eblank);
    dp_kernel<<<2 * B_DIM, 64, 0, stream>>>(epair, eblank, labels, label_length,
                                            data_length, alphavec, betavec, kaccs);
    combine_kernel<<<B_DIM, 64, 0, stream>>>(alphavec, betavec, kaccs, labels, lossb);
    final_kernel<<<1, 64, 0, stream>>>(lossb, out);
}

// Round 6
// 241.909 us; speedup vs baseline: 3.8291x; 1.0504x over previous
//
#include <hip/hip_runtime.h>
#include <hip/hip_bf16.h>

// CTC loss, fp32 in / fp32 out. T=1024, B=32, C=1024, L=128 fixed.
// R6: R4's fp64 meet-in-the-middle DP (absmax 0.0) + register-rotation
//     prefetch (distance 3) of emissions from LDS so the per-step chain is
//     only shfl(a3) + 3 dependent f64 ops (~31 cyc), not LDS latency.
//     (R5's fp32 DP failed: 8-step renorm window spans ~50 ln units; winner
//      paths sit 40-100 ln below running max -> 2^-126 flush ate real mass.)
#define T_DIM 1024
#define B_DIM 32
#define C_DIM 1024
#define L_DIM 128
#define S_DIM 257
#define CH    32          // timesteps per staged chunk

// ---- workspace layout (bytes) ----
#define WS_EPAIR   0                                  // [B][T][64] float2 = 16 MiB
#define WS_EBLANK  (32u * 1024u * 64u * 8u)           // [B][T] float
#define WS_ALPHA   (WS_EBLANK + 32u * 1024u * 4u)     // [B][264] double
#define WS_BETA    (WS_ALPHA + 32u * 264u * 8u)       // [B][264] double (257,258 = 0)
#define WS_KACC    (WS_BETA + 32u * 264u * 8u)        // [B][2] long long

// ---------------- Kernel 1: log-softmax + linear emission gather ----------------
__global__ __launch_bounds__(256) void emit_kernel(const float* __restrict__ data,
                                                   const int* __restrict__ labels,
                                                   float2* __restrict__ epair,
                                                   float* __restrict__ eblank) {
    const int wave = threadIdx.x >> 6;
    const int lane = threadIdx.x & 63;
    const int row = blockIdx.x * 4 + wave;           // row = t*B + b
    const int b = row & (B_DIM - 1);
    const int t = row >> 5;                          // B = 32

    const float4* d4 = (const float4*)(data + (size_t)row * C_DIM);
    float4 v[4];
    float m = -3.4e38f;
#pragma unroll
    for (int k = 0; k < 4; ++k) {
        v[k] = d4[lane + 64 * k];
        m = fmaxf(m, fmaxf(fmaxf(v[k].x, v[k].y), fmaxf(v[k].z, v[k].w)));
    }
#pragma unroll
    for (int off = 32; off >= 1; off >>= 1)
        m = fmaxf(m, __shfl_xor(m, off, 64));
    float s = 0.f;
#pragma unroll
    for (int k = 0; k < 4; ++k)
        s += __expf(v[k].x - m) + __expf(v[k].y - m) +
             __expf(v[k].z - m) + __expf(v[k].w - m);
#pragma unroll
    for (int off = 32; off >= 1; off >>= 1)
        s += __shfl_xor(s, off, 64);
    const float lse = m + __logf(s);

    const float* drow = data + (size_t)row * C_DIM;
    const int2 cc = ((const int2*)(labels + b * L_DIM))[lane];   // labels 2l, 2l+1
    float2 pr;
    pr.x = __expf(drow[cc.x] - lse);
    pr.y = __expf(drow[cc.y] - lse);
    epair[((size_t)b * T_DIM + t) * 64 + lane] = pr;             // b-major rows
    if (lane == 0) eblank[b * T_DIM + t] = __expf(drow[0] - lse);
}

// ---------------- Kernel 2: alpha/beta DP (fp64 linear, prefetched) ----------------
// grid = 64 blocks: b = blockIdx&31, dir = blockIdx>>5 (0=fwd alpha, 1=bwd beta).
// One wave per block. Lane l owns 4 states; one shfl_up(a3) per step.
__global__ __launch_bounds__(64, 1) void dp_kernel(const float2* __restrict__ epair,
                                                   const float* __restrict__ eblank,
                                                   const int* __restrict__ labels,
                                                   const int* __restrict__ label_length,
                                                   const int* __restrict__ data_length,
                                                   double* __restrict__ alphavec,
                                                   double* __restrict__ betavec,
                                                   long long* __restrict__ kaccs) {
    const int b   = blockIdx.x & (B_DIM - 1);
    const int dir = blockIdx.x >> 5;
    const int l = threadIdx.x;
    const int* lab = labels + b * L_DIM;
    const int len = label_length[b];
    const int dlen = data_length[b];
    const int m = dlen >> 1;          // split point: alpha(m-1) meets beta(m)

    __shared__ float2 ebuf[2][CH][64];   // 32 KiB double buffer
    __shared__ float  ebl[T_DIM];        // whole blank row, 4 KiB

    const float2* eprow = epair + (size_t)b * T_DIM * 64;
    const float*  ebrow = eblank + (size_t)b * T_DIM;

    // Stage entire blank row: 16 x (64 lanes x 4 B).
#pragma unroll
    for (int i = 0; i < T_DIM / 64; ++i)
        __builtin_amdgcn_global_load_lds(
            (const __attribute__((address_space(1))) void*)(ebrow + i * 64 + l),
            (__attribute__((address_space(3))) void*)(&ebl[i * 64]), 4, 0, 0);

    // Stage CH epair rows [trow0, trow0+CH) : 16 x (64 lanes x 16 B), 2 rows/instr.
    auto stage_chunk = [&](int cb, int trow0) {
#pragma unroll
        for (int i = 0; i < CH / 2; ++i)
            __builtin_amdgcn_global_load_lds(
                (const __attribute__((address_space(1))) void*)
                    ((const char*)(eprow + (size_t)(trow0 + 2 * i) * 64) + l * 16),
                (__attribute__((address_space(3))) void*)(&ebuf[cb][2 * i][0]), 16, 0, 0);
    };

    double a0 = 0.0, a1 = 0.0, a2 = 0.0, a3 = 0.0, a4 = 0.0;
    long long kacc = 0;

    // em1 multiplies state 4l+1, em3 multiplies state 4l+3 (fwd: ep.x/ep.y;
    // bwd reversed: ep.y/ep.x). skip1d/skip3d set per-direction below.
    double skip1d, skip3d;
    auto step = [&](double em1, double em3, double eb) {
        double h = __shfl_up(a3, 1, 64);
        if (l == 0) h = 0.0;
        const double n0 = (a0 + h) * eb;
        const double n1 = fma(skip1d, h, a1 + a0) * em1;
        const double n2 = (a2 + a1) * eb;
        const double n3 = fma(skip3d, a1, a3 + a2) * em3;
        const double n4 = (a4 + a3) * eb;
        a0 = n0; a1 = n1; a2 = n2; a3 = n3; a4 = n4;
    };

    auto renorm = [&]() {
        double mx = fmax(fmax(fmax(a0, a1), fmax(a2, a3)), a4);
        int hi = __double2hiint(mx);            // alphas >= 0: hi-word order = value order
#pragma unroll
        for (int off = 32; off >= 1; off >>= 1)
            hi = max(hi, __shfl_xor(hi, off, 64));
        const int ex = ((hi >> 20) & 0x7ff) - 1023;
        const double sc = __hiloint2double((1023 - ex) << 20, 0);   // 2^-ex
        a0 *= sc; a1 *= sc; a2 *= sc; a3 *= sc; a4 *= sc;
        kacc += ex;
    };

    if (dir == 0) {
        // ---------------- forward alpha: t = 0 .. m-1 ----------------
        const int2 cc = ((const int2*)lab)[l];                        // labels 2l, 2l+1
        skip1d = ((l > 0) && (cc.x != lab[2 * l - 1])) ? 1.0 : 0.0;
        skip3d = (cc.y != cc.x) ? 1.0 : 0.0;

        stage_chunk(0, 1);
        __builtin_amdgcn_s_waitcnt(0x0f70);     // vmcnt(0)

        {   // t = 0 init
            const float2 ep0 = eprow[l];
            a0 = (l == 0) ? (double)ebl[0] : 0.0;
            a1 = (l == 0) ? (double)ep0.x : 0.0;
        }

        const int nsteps = m - 1;               // t = 1 .. m-1
        const int nch = (nsteps + CH - 1) / CH;
        for (int c = 0; c < nch; ++c) {
            const int cb = c & 1;
            const bool more = (c + 1 < nch);
            if (more) stage_chunk(cb ^ 1, 1 + CH * (c + 1));
            __builtin_amdgcn_sched_barrier(0);
            const int t0 = 1 + CH * c;
            if (t0 + CH <= m) {
                // full chunk: branch-free body, distance-3 register rotation
                double e1R[4], e2R[4], ebR[4];
#pragma unroll
                for (int p = 0; p < 3; ++p) {
                    const float2 ep = ebuf[cb][p][l];
                    e1R[p] = (double)ep.x; e2R[p] = (double)ep.y;
                    ebR[p] = (double)ebl[t0 + p];
                }
#pragma unroll
                for (int j = 0; j < CH; ++j) {
                    const int jn = (j + 3 < CH) ? (j + 3) : (CH - 1);
                    const float2 epn = ebuf[cb][jn][l];
                    const float ebn = ebl[t0 + jn];
                    step(e1R[j & 3], e2R[j & 3], ebR[j & 3]);
                    e1R[(j + 3) & 3] = (double)epn.x;
                    e2R[(j + 3) & 3] = (double)epn.y;
                    ebR[(j + 3) & 3] = (double)ebn;
                }
            } else {
                // tail chunk (once): predicated, plain LDS reads
#pragma unroll
                for (int j = 0; j < CH; ++j) {
                    if (t0 + j < m) {
                        const float2 ep = ebuf[cb][j][l];
                        step((double)ep.x, (double)ep.y, (double)ebl[t0 + j]);
                    }
                }
            }
            renorm();
            if (more) __builtin_amdgcn_s_waitcnt(0x0f70);
            __builtin_amdgcn_sched_barrier(0);
        }

        double* av = alphavec + b * 264;
        av[4 * l + 0] = a0; av[4 * l + 1] = a1;
        av[4 * l + 2] = a2; av[4 * l + 3] = a3;
        if (l == 63) av[256] = a4;
        if (l == 0) kaccs[2 * b + 0] = kacc;
    } else {
        // ---------------- backward beta: t = dlen-1 .. m (reversed states r=256-s) ----
        const int2 c2 = ((const int2*)lab)[63 - l];    // (lab[126-2l], lab[127-2l])
        const int labL = (l > 0) ? lab[128 - 2 * l] : -1;
        skip1d = ((l > 0) && (labL != c2.y)) ? 1.0 : 0.0;   // r=4l+1
        skip3d = (c2.y != c2.x) ? 1.0 : 0.0;                // r=4l+3

        stage_chunk(0, dlen - 1 - CH);          // rows [dlen-1-CH, dlen-2]
        __builtin_amdgcn_s_waitcnt(0x0f70);

        {   // init at t = dlen-1: beta = e * [s==2len || s==2len-1],  s = 256-r
            const float2 epi = eprow[(size_t)(dlen - 1) * 64 + (63 - l)];
            const double ebi = (double)ebl[dlen - 1];
            const int s0 = 256 - 4 * l;
            a0 = (s0 == 2 * len     || s0 == 2 * len - 1) ? ebi : 0.0;
            a1 = (s0 - 1 == 2 * len || s0 - 1 == 2 * len - 1) ? (double)epi.y : 0.0;
            a2 = (s0 - 2 == 2 * len || s0 - 2 == 2 * len - 1) ? ebi : 0.0;
            a3 = (s0 - 3 == 2 * len || s0 - 3 == 2 * len - 1) ? (double)epi.x : 0.0;
            a4 = 0.0;                            // lane63's r=256 is s=0, never terminal
        }

        const int nsteps = dlen - 1 - m;        // t = dlen-2 .. m
        const int nch = (nsteps + CH - 1) / CH;
        for (int c = 0; c < nch; ++c) {
            const int cb = c & 1;
            const bool more = (c + 1 < nch);
            const int thi = dlen - 2 - CH * c;
            const int tlo = thi - CH + 1;
            if (more) stage_chunk(cb ^ 1, tlo - CH);
            __builtin_amdgcn_sched_barrier(0);
            if (tlo >= m) {
                // full chunk: jj ascending = t descending; em1 = ep.y, em3 = ep.x
                double e1R[4], e2R[4], ebR[4];
#pragma unroll
                for (int p = 0; p < 3; ++p) {
                    const float2 ep = ebuf[cb][CH - 1 - p][63 - l];
                    e1R[p] = (double)ep.y; e2R[p] = (double)ep.x;
                    ebR[p] = (double)ebl[thi - p];
                }
#pragma unroll
                for (int jj = 0; jj < CH; ++jj) {
                    const int jnn = (jj + 3 < CH) ? (jj + 3) : (CH - 1);
                    const float2 epn = ebuf[cb][CH - 1 - jnn][63 - l];
                    const float ebn = ebl[thi - jnn];
                    step(e1R[jj & 3], e2R[jj & 3], ebR[jj & 3]);
                    e1R[(jj + 3) & 3] = (double)epn.y;
                    e2R[(jj + 3) & 3] = (double)epn.x;
                    ebR[(jj + 3) & 3] = (double)ebn;
                }
            } else {
                // tail chunk (once): predicated
#pragma unroll
                for (int jj = 0; jj < CH; ++jj) {
                    const int j = CH - 1 - jj;
                    const int t = tlo + j;
                    if (t >= m) {
                        const float2 ep = ebuf[cb][j][63 - l];
                        step((double)ep.y, (double)ep.x, (double)ebl[t]);
                    }
                }
            }
            renorm();
            if (more) __builtin_amdgcn_s_waitcnt(0x0f70);
            __builtin_amdgcn_sched_barrier(0);
        }

        double* bv = betavec + b * 264;               // natural s order
        bv[256 - 4 * l] = a0; bv[255 - 4 * l] = a1;
        bv[254 - 4 * l] = a2; bv[253 - 4 * l] = a3;
        if (l == 63) bv[0] = a4;
        if (l == 0) { bv[257] = 0.0; bv[258] = 0.0; kaccs[2 * b + 1] = kacc; }
    }
}

// ---------------- Kernel 3: combine alpha(m-1) x T x beta(m), mean over b ----------
// Single block, 4 waves; wave w handles b = w, w+4, ..., w+28.
__global__ __launch_bounds__(256) void combine_kernel(const double* __restrict__ alphavec,
                                                      const double* __restrict__ betavec,
                                                      const long long* __restrict__ kaccs,
                                                      const int* __restrict__ labels,
                                                      float* __restrict__ out) {
    const int wave = threadIdx.x >> 6;
    const int l = threadIdx.x & 63;
    float acc = 0.f;

    for (int b = wave; b < B_DIM; b += 4) {
        const double* A = alphavec + b * 264;
        const double* Bv = betavec + b * 264;
        const int* lab = labels + b * L_DIM;

        const double a0 = A[4 * l], a1 = A[4 * l + 1], a2 = A[4 * l + 2], a3 = A[4 * l + 3];
        const double b0 = Bv[4 * l], b1 = Bv[4 * l + 1], b2 = Bv[4 * l + 2];
        const double b3 = Bv[4 * l + 3], b4 = Bv[4 * l + 4], b5 = Bv[4 * l + 5];
        const double sk1 = (lab[2 * l + 1] != lab[2 * l]) ? 1.0 : 0.0;        // into 4l+3
        const int labn = (l < 63) ? lab[2 * l + 2] : -1;
        const double sk3 = ((l < 63) && (labn != lab[2 * l + 1])) ? 1.0 : 0.0; // into 4l+5

        double s = a0 * (b0 + b1)
                 + a1 * (b1 + b2 + sk1 * b3)
                 + a2 * (b2 + b3)
                 + a3 * (b3 + b4 + sk3 * b5);
        if (l == 63) s += A[256] * Bv[256];

#pragma unroll
        for (int off = 32; off >= 1; off >>= 1)
            s += __shfl_xor(s, off, 64);

        if (l == 0) {
            const long long k = kaccs[2 * b] + kaccs[2 * b + 1];
            const long long vb = __double_as_longlong(s);
            const int ve = (int)((vb >> 52) & 0x7ff) - 1023;
            const double mant = __longlong_as_double(
                (vb & 0x000FFFFFFFFFFFFFLL) | (1023LL << 52));        // [1,2)
            const double l2 = (double)__log2f((float)mant) + (double)ve + (double)k;
            acc += (float)(-l2 * 0.6931471805599453);
        }
    }

    __shared__ float part[4];
    if (l == 0) part[wave] = acc;
    __syncthreads();
    if (threadIdx.x == 0)
        out[0] = (part[0] + part[1] + part[2] + part[3]) * (1.0f / B_DIM);
}

extern "C" void kernel_launch(void* const* d_in, const int* in_sizes, int n_in,
                              void* d_out, int out_size, void* d_ws, size_t ws_size,
                              hipStream_t stream) {
    const int*   labels       = (const int*)d_in[0];
    const float* data         = (const float*)d_in[1];
    const int*   label_length = (const int*)d_in[2];
    const int*   data_length  = (const int*)d_in[3];
    float*       out          = (float*)d_out;

    char* ws = (char*)d_ws;
    float2*    epair    = (float2*)(ws + WS_EPAIR);
    float*     eblank   = (float*)(ws + WS_EBLANK);
    double*    alphavec = (double*)(ws + WS_ALPHA);
    double*    betavec  = (double*)(ws + WS_BETA);
    long long* kaccs    = (long long*)(ws + WS_KACC);

    const int rows = T_DIM * B_DIM;
    emit_kernel<<<rows / 4, 256, 0, stream>>>(data, labels, epair, eblank);
    dp_kernel<<<2 * B_DIM, 64, 0, stream>>>(epair, eblank, labels, label_length,
                                            data_length, alphavec, betavec, kaccs);
    combine_kernel<<<1, 256, 0, stream>>>(alphavec, betavec, kaccs, labels, out);
}